// Round 4
// baseline (696.026 us; speedup 1.0000x reference)
//
#include <hip/hip_runtime.h>
#include <stdint.h>

#define B_N 512
#define E_N 1024
#define ML_N 50
#define V_N 50000
#define V_PAD 50048   // 391 * 128

typedef __bf16 bf16_t;
typedef __bf16 bf16x8 __attribute__((ext_vector_type(8)));
typedef float f32x4 __attribute__((ext_vector_type(4)));

__device__ __forceinline__ uint16_t f2bf(float f) {
    union { float f; uint32_t u; } v; v.f = f;
    return (uint16_t)((v.u + 0x7FFFu + ((v.u >> 16) & 1u)) >> 16);  // RNE
}
__device__ __forceinline__ uint32_t packbf2(float lo, float hi) {
    return (uint32_t)f2bf(lo) | ((uint32_t)f2bf(hi) << 16);
}
__device__ __forceinline__ void load_lds16(const void* g, void* l) {
    __builtin_amdgcn_global_load_lds((const __attribute__((address_space(1))) void*)g,
                                     (__attribute__((address_space(3))) void*)l, 16, 0, 0);
}

// ---------------------------------------------------------------------------
// K0: classify padded_positions dtype: 0 = int32 {0,1}, 1 = float32 {0,1.0f},
// 2 = byte. Reads first 25600 bytes (in-bounds under every interpretation).
__global__ __launch_bounds__(256) void detect_mask_mode(const uint32_t* __restrict__ mp,
                                                        int* __restrict__ mode_out) {
    __shared__ int s_int_ok, s_flt_ok;
    if (threadIdx.x == 0) { s_int_ok = 1; s_flt_ok = 1; }
    __syncthreads();
    int int_ok = 1, flt_ok = 1;
    for (int i = threadIdx.x; i < 6400; i += 256) {
        uint32_t v = mp[i];
        if (!(v == 0u || v == 1u)) int_ok = 0;
        if (!(v == 0u || v == 0x3F800000u)) flt_ok = 0;
    }
    if (!int_ok) atomicAnd(&s_int_ok, 0);
    if (!flt_ok) atomicAnd(&s_flt_ok, 0);
    __syncthreads();
    if (threadIdx.x == 0) *mode_out = s_int_ok ? 0 : (s_flt_ok ? 1 : 2);
}

// ---------------------------------------------------------------------------
// K1 fused: energies + masked softmax + contexts + embed gather.
// One block per batch row, 512 threads. Pass 1 streams enc (HBM); pass 2
// re-reads the same 205 KB slice (L2/LLC-hot).
__global__ __launch_bounds__(512) void attn_kernel(
    const float* __restrict__ enc, const float* __restrict__ h0,
    const void* __restrict__ maskp, const int* __restrict__ mode_p,
    const int* __restrict__ ts, const float* __restrict__ emb,
    float* __restrict__ ctx_f, bf16_t* __restrict__ ctx_bf,
    bf16_t* __restrict__ words_bf)
{
    __shared__ float hs[E_N];
    __shared__ float en[64];
    __shared__ float nrm[64];

    int b = blockIdx.x;
    int tid = threadIdx.x;
    int lane = tid & 63, wv = tid >> 6;   // 8 waves

    if (tid < 256)
        ((float4*)hs)[tid] = ((const float4*)(h0 + (size_t)b * E_N))[tid];
    __syncthreads();

    const float* encb = enc + (size_t)b * ML_N * E_N;

    // pass 1: energies (one row per wave, strided by 8)
    for (int l = wv; l < ML_N; l += 8) {
        const float4* row = (const float4*)(encb + l * E_N);
        float acc = 0.f;
        #pragma unroll
        for (int t = 0; t < 4; t++) {
            float4 e4 = row[lane + 64 * t];
            float4 h4 = ((const float4*)hs)[lane + 64 * t];
            acc += e4.x * h4.x + e4.y * h4.y + e4.z * h4.z + e4.w * h4.w;
        }
        #pragma unroll
        for (int off = 32; off > 0; off >>= 1) acc += __shfl_down(acc, off, 64);
        if (lane == 0) en[l] = acc;
    }
    __syncthreads();

    // masked softmax on wave 0
    if (tid < 64) {
        int mode = *mode_p;
        float e = (lane < ML_N) ? en[lane] : -1e30f;
        int pad = 0;
        if (lane < ML_N) {
            int mi = b * ML_N + lane;
            if (mode == 0)      pad = (((const int*)maskp)[mi] != 0);
            else if (mode == 1) pad = (((const float*)maskp)[mi] != 0.0f);
            else                pad = (((const unsigned char*)maskp)[mi] != 0);
        }
        float m = e;
        #pragma unroll
        for (int off = 32; off > 0; off >>= 1) m = fmaxf(m, __shfl_down(m, off, 64));
        m = __shfl(m, 0, 64);
        float x = (lane < ML_N && !pad) ? __expf(e - m) : 0.f;
        float s = x;
        #pragma unroll
        for (int off = 32; off > 0; off >>= 1) s += __shfl_down(s, off, 64);
        s = __shfl(s, 0, 64);
        nrm[lane] = x / s;
    }
    __syncthreads();

    // pass 2: contexts (two consecutive e per thread; enc re-read is cache-hot)
    float acc0 = 0.f, acc1 = 0.f;
    const float2* encb2 = (const float2*)encb;
    #pragma unroll 10
    for (int l = 0; l < ML_N; l++) {
        float2 v = encb2[l * 512 + tid];
        float w = nrm[l];
        acc0 += w * v.x;
        acc1 += w * v.y;
    }
    ((float2*)(ctx_f + (size_t)b * E_N))[tid] = make_float2(acc0, acc1);
    ((uint32_t*)(ctx_bf + (size_t)b * E_N))[tid] = packbf2(acc0, acc1);

    int wid = ts[b];
    float2 w2 = ((const float2*)(emb + (size_t)wid * E_N))[tid];
    ((uint32_t*)(words_bf + (size_t)b * E_N))[tid] = packbf2(w2.x, w2.y);
}

// ---------------------------------------------------------------------------
// K2: bf16-MFMA GEMM, T3+T4 pipelined: 128x128 tile, BK=64, double-buffered
// LDS (64 KB), ONE barrier per K-step, counted vmcnt (never 0 in steady
// state; 8 B-loads stay in flight across each barrier). K MUST be a
// multiple of 64 with K/64 >= 2 (both call sites use K=1024 -> nt=16).
//   A: bf16, staged via global_load_lds (linear dest, PRE-SWIZZLED source).
//   B: fp32, reg-staged (8x dwordx4) -> cast bf16 -> swizzled ds_write_b128
//      (fused conversion, no separate pass, no extra HBM traffic).
// Both LDS tiles are [128][64] bf16 with chunk-XOR swizzle
//   lds[r][cc ^ (r&7)] = global[r][cc]  (16B chunks) so the fragment
// ds_read_b128 (row stride 128 B, otherwise 16-way conflict, G4) spreads
// across banks. Read offset XOR uses row&7 == l16&7 on both tiles.
// vmcnt ledger (issue order guarantees oldest-first drain, so these are
// conservative even if the compiler splits loads):
//   entry: 8 (B(t+1))  -> +STAGE_A 4 = 12 -> vmcnt(4) drains B(t+1)
//   +LOAD_B(t+2) 8 = 12 -> pre-barrier vmcnt(8) drains A(t+1); B(t+2) flies.
// Each inline s_waitcnt is followed by sched_barrier(0) (rule #18 class:
// forbid scheduler migration across the counted wait).
// Dual-pair: blocks [0,bpp) do out0 = A0@B0^T, [bpp,2bpp) out1 = A1@B1^T.
// Grid: XCD-bijective chunked remap, m-fastest (B panel L2/LLC reuse).
__global__ __launch_bounds__(256) void gemm_rs(
    const bf16_t* __restrict__ A0, const float* __restrict__ B0,
    const bf16_t* __restrict__ A1, const float* __restrict__ B1,
    const float* __restrict__ bias, float* __restrict__ out0,
    float* __restrict__ out1, int M, int N, int K, int mtiles, int bpp)
{
    __shared__ __align__(16) bf16_t As[2][128 * 64];   // 32 KB
    __shared__ __align__(16) bf16_t Bs[2][128 * 64];   // 32 KB

    int tid = threadIdx.x;
    int lane = tid & 63, wv = tid >> 6;
    int quad = lane >> 4, l16 = lane & 15;

    // XCD-bijective chunked remap (m204)
    int nwg = (int)gridDim.x, bid = (int)blockIdx.x;
    int q = nwg >> 3, r = nwg & 7;
    int xcd = bid & 7, idx = bid >> 3;
    int wg = (xcd < r ? xcd * (q + 1) : r * (q + 1) + (xcd - r) * q) + idx;

    int pair = wg / bpp;
    int rr_wg = wg - pair * bpp;
    int m0 = (rr_wg % mtiles) * 128;
    int n0 = (rr_wg / mtiles) * 128;

    const bf16_t* A = pair ? A1 : A0;
    const float*  B = pair ? B1 : B0;
    float*        out = pair ? out1 : out0;

    int wm = (wv >> 1) * 64, wn = (wv & 1) * 64;

    f32x4 acc[4][4];
    #pragma unroll
    for (int a = 0; a < 4; a++)
        #pragma unroll
        for (int b2 = 0; b2 < 4; b2++) { f32x4 z = {0.f, 0.f, 0.f, 0.f}; acc[a][b2] = z; }

    // A staging: load i_ covers LDS chunks [wv*64 + i_*256 + lane]; that chunk
    // is row (wv*8 + 32*i_ + (lane>>3)), dest col-chunk (lane&7). Source
    // col-chunk = (lane&7) ^ (row&7) = (lane&7) ^ (lane>>3).
    int rA0 = wv * 8 + (lane >> 3);
    int cA  = ((lane & 7) ^ (lane >> 3)) * 8;
    const bf16_t* aq = A + (size_t)(m0 + rA0) * K + cA;

    // B staging: thread covers local row rB = tid>>1, col-half hB = tid&1
    // (32 fp32 = 8 float4 per thread per K-step).
    int rB = tid >> 1, hB = tid & 1;
    int growB = n0 + rB; if (growB > N - 1) growB = N - 1;   // tail clamp
    const float* bq = B + (size_t)growB * K + hB * 32;

    float4 c[8];

#define STAGE_A(dst, k0) do {                                             \
        _Pragma("unroll")                                                 \
        for (int i_ = 0; i_ < 4; i_++)                                    \
            load_lds16(aq + (size_t)(32 * i_) * K + (k0),                 \
                       (dst) + wv * 512 + i_ * 2048);                     \
    } while (0)

#define LOAD_B(k0) do {                                                   \
        const float4* p_ = (const float4*)(bq + (k0));                    \
        _Pragma("unroll")                                                 \
        for (int j_ = 0; j_ < 8; j_++) c[j_] = p_[j_];                    \
    } while (0)

#define WRITE_B(dst) do {                                                 \
        _Pragma("unroll")                                                 \
        for (int j_ = 0; j_ < 4; j_++) {                                  \
            float4 x_ = c[2 * j_], y_ = c[2 * j_ + 1];                    \
            bf16x8 w_;                                                    \
            w_[0] = (bf16_t)x_.x; w_[1] = (bf16_t)x_.y;                   \
            w_[2] = (bf16_t)x_.z; w_[3] = (bf16_t)x_.w;                   \
            w_[4] = (bf16_t)y_.x; w_[5] = (bf16_t)y_.y;                   \
            w_[6] = (bf16_t)y_.z; w_[7] = (bf16_t)y_.w;                   \
            int jj_ = (hB * 4 + j_) ^ (rB & 7);                           \
            *(bf16x8*)((dst) + rB * 64 + jj_ * 8) = w_;                   \
        }                                                                 \
    } while (0)

#define WAITCNT(s) do {                                                   \
        asm volatile(s ::: "memory");                                     \
        __builtin_amdgcn_sched_barrier(0);                                \
    } while (0)

    int nt = K >> 6;    // call sites guarantee nt == 16

    // ---- prologue: stage tile 0, pre-issue B(1) regs
    LOAD_B(0);
    STAGE_A(&As[0][0], 0);
    WAITCNT("s_waitcnt vmcnt(4)");           // B(0) regs landed; fence
    WRITE_B(&Bs[0][0]);
    LOAD_B(64);
    WAITCNT("s_waitcnt vmcnt(8) lgkmcnt(0)"); // A(0) in LDS; B(1) flying
    __builtin_amdgcn_s_barrier();

    #pragma unroll 1
    for (int t = 0; t < nt; ++t) {
        int cur = t & 1, nxt = cur ^ 1;

        if (t + 1 < nt) STAGE_A(&As[nxt][0], (t + 1) << 6);
        WAITCNT("s_waitcnt vmcnt(4)");       // B(t+1) regs landed; fence
        if (t + 1 < nt) WRITE_B(&Bs[nxt][0]);
        if (t + 2 < nt) LOAD_B((t + 2) << 6);

        const bf16_t* Ac = &As[cur][0];
        const bf16_t* Bc = &Bs[cur][0];
        #pragma unroll
        for (int kh = 0; kh < 2; kh++) {
            bf16x8 af[4], bfr[4];
            #pragma unroll
            for (int i = 0; i < 4; i++) {
                int xo = ((kh * 4 + quad) ^ (l16 & 7)) * 8;
                af[i]  = *(const bf16x8*)(Ac + (wm + i * 16 + l16) * 64 + xo);
                bfr[i] = *(const bf16x8*)(Bc + (wn + i * 16 + l16) * 64 + xo);
            }
            #pragma unroll
            for (int mi = 0; mi < 4; mi++)
                #pragma unroll
                for (int ni = 0; ni < 4; ni++)
                    acc[mi][ni] = __builtin_amdgcn_mfma_f32_16x16x32_bf16(
                        af[mi], bfr[ni], acc[mi][ni], 0, 0, 0);
        }

        if (t + 1 < nt) {
            if (t + 2 < nt) {
                WAITCNT("s_waitcnt vmcnt(8) lgkmcnt(0)");  // drain A(t+1) only
            } else {
                WAITCNT("s_waitcnt vmcnt(0) lgkmcnt(0)");  // tail: full drain
            }
            __builtin_amdgcn_s_barrier();
        }
    }
#undef STAGE_A
#undef LOAD_B
#undef WRITE_B
#undef WAITCNT

    #pragma unroll
    for (int mi = 0; mi < 4; mi++) {
        int gm = m0 + wm + mi * 16 + quad * 4;
        #pragma unroll
        for (int ni = 0; ni < 4; ni++) {
            int gn = n0 + wn + ni * 16 + l16;
            if (gn < N) {
                float bs = bias ? bias[gn] : 0.f;
                #pragma unroll
                for (int rw = 0; rw < 4; rw++)
                    out[(size_t)(gm + rw) * N + gn] = acc[mi][ni][rw] + bs;
            }
        }
    }
}

// ---------------------------------------------------------------------------
// K3: LSTM cell elementwise. gates = g0 + g1 + b_ih + b_hh (the two GEMM
// halves: words@w_ih^T and ctx@w_hh^T, biases folded here).
__global__ __launch_bounds__(256) void lstm_cell(
    const float* __restrict__ g0p, const float* __restrict__ g1p,
    const float* __restrict__ b_ih, const float* __restrict__ b_hh,
    const float* __restrict__ ctx,
    float* __restrict__ h_out, float* __restrict__ c_out,
    uint16_t* __restrict__ h_bf)
{
    int idx = blockIdx.x * 256 + threadIdx.x;
    int b = idx >> 10, e = idx & 1023;
    const float* g0 = g0p + ((size_t)b << 12);
    const float* g1 = g1p + ((size_t)b << 12);
    float iv = g0[e]        + g1[e]        + b_ih[e]        + b_hh[e];
    float fv = g0[e + 1024] + g1[e + 1024] + b_ih[e + 1024] + b_hh[e + 1024];
    float gv = g0[e + 2048] + g1[e + 2048] + b_ih[e + 2048] + b_hh[e + 2048];
    float ov = g0[e + 3072] + g1[e + 3072] + b_ih[e + 3072] + b_hh[e + 3072];
    iv = 1.f / (1.f + __expf(-iv));
    fv = 1.f / (1.f + __expf(-fv));
    gv = tanhf(gv);
    ov = 1.f / (1.f + __expf(-ov));
    float c = fv * ctx[idx] + iv * gv;
    float h = ov * tanhf(c);
    c_out[idx] = c;
    h_out[idx] = h;
    h_bf[idx] = f2bf(h);
}

// ---------------------------------------------------------------------------
extern "C" void kernel_launch(void* const* d_in, const int* in_sizes, int n_in,
                              void* d_out, int out_size, void* d_ws, size_t ws_size,
                              hipStream_t stream)
{
    const int*   ts     = (const int*)d_in[0];
    const float* enc    = (const float*)d_in[1];
    const float* h0     = (const float*)d_in[2];
    const void*  mask   = d_in[4];
    const float* emb    = (const float*)d_in[6];
    const float* w_ih   = (const float*)d_in[7];
    const float* w_hh   = (const float*)d_in[8];
    const float* b_ih   = (const float*)d_in[9];
    const float* b_hh   = (const float*)d_in[10];
    const float* w_proj = (const float*)d_in[11];
    const float* b_proj = (const float*)d_in[12];
    float* out = (float*)d_out;

    // ws layout (~21.3 MB total)
    char* ws = (char*)d_ws;
    size_t off = 0;
    int*      mode     = (int*)(ws + off);      off += 256;
    float*    ctx_f    = (float*)(ws + off);    off += (size_t)B_N * E_N * 4;    // 2 MB
    bf16_t*   ctx_bf   = (bf16_t*)(ws + off);   off += (size_t)B_N * E_N * 2;    // 1 MB
    bf16_t*   words_bf = (bf16_t*)(ws + off);   off += (size_t)B_N * E_N * 2;    // 1 MB
    uint16_t* h_bf     = (uint16_t*)(ws + off); off += (size_t)B_N * E_N * 2;    // 1 MB
    float*    gates0   = (float*)(ws + off);    off += (size_t)B_N * 4096 * 4;   // 8 MB
    float*    gates1   = (float*)(ws + off);    off += (size_t)B_N * 4096 * 4;   // 8 MB

    float* h_out = out + (size_t)B_N * V_N;
    float* c_out = h_out + (size_t)B_N * E_N;

    detect_mask_mode<<<1, 256, 0, stream>>>((const uint32_t*)mask, mode);
    attn_kernel<<<B_N, 512, 0, stream>>>(enc, h0, mask, mode, ts, emb,
                                         ctx_f, ctx_bf, words_bf);

    // gates halves: g0 = words @ w_ih^T, g1 = ctx @ w_hh^T
    // (M=512, N=4096, K=1024 each; 2 pairs x 128 blocks)
    gemm_rs<<<256, 256, 0, stream>>>(words_bf, w_ih, ctx_bf, w_hh, nullptr,
                                     gates0, gates1, B_N, 4096, 1024, 4, 128);

    lstm_cell<<<(B_N * E_N) / 256, 256, 0, stream>>>(gates0, gates1, b_ih, b_hh,
                                                     ctx_f, h_out, c_out, h_bf);

    // logits = h_new @ w_proj^T + b_proj   (M=512, N=50000, K=1024)
    gemm_rs<<<1564, 256, 0, stream>>>((const bf16_t*)h_bf, w_proj,
                                      (const bf16_t*)h_bf, w_proj, b_proj,
                                      out, out, B_N, V_N, 1024, 4, 1564);
}